// Round 6
// baseline (598.132 us; speedup 1.0000x reference)
//
#include <hip/hip_runtime.h>
#include <hip/hip_bf16.h>
#include <stdint.h>

// Problem constants: B=4, T=2048, C=1024, H=16, D=64. Inputs f32, output f32.
#define B_ 4
#define T_ 2048
#define C_ 1024
#define H_ 16
#define D_ 64

typedef __bf16 bf16;
typedef _Float16 f16;
typedef __attribute__((ext_vector_type(8))) __bf16 bf16x8;
typedef __attribute__((ext_vector_type(4))) __bf16 bf16x4;
typedef __attribute__((ext_vector_type(4))) _Float16 f16x4;
typedef __attribute__((ext_vector_type(4))) float floatx4;

__device__ __forceinline__ floatx4 mfma16(bf16x8 a, bf16x8 b, floatx4 c) {
  return __builtin_amdgcn_mfma_f32_16x16x32_bf16(a, b, c, 0, 0, 0);
}
__device__ __forceinline__ floatx4 mfma_pv(f16x4 a, f16x4 b, floatx4 c) {
  return __builtin_amdgcn_mfma_f32_16x16x16f16(a, b, c, 0, 0, 0);
}

__device__ __forceinline__ void gl_lds16(const void* g, void* l) {
  __builtin_amdgcn_global_load_lds(
      (__attribute__((address_space(1))) uint32_t*)g,
      (__attribute__((address_space(3))) uint32_t*)l, 16, 0, 0);
}

// ---------------- f32 -> bf16 bulk convert ----------------
__global__ __launch_bounds__(256) void cvt_bf16(const float* __restrict__ in,
                                                bf16* __restrict__ out) {
  const size_t i = ((size_t)blockIdx.x * 256 + threadIdx.x) * 4;
  const floatx4 v = *(const floatx4*)(in + i);
  bf16x4 r;
#pragma unroll
  for (int j = 0; j < 4; j++) r[j] = (bf16)v[j];
  *(bf16x4*)(out + i) = r;
}

// ---------------- transpose: in[K][N] f32 -> out[N][K] bf16 ----------------
__global__ __launch_bounds__(256) void transpose_f32(const float* __restrict__ in,
                                                     bf16* __restrict__ out,
                                                     int K, int N) {
  __shared__ bf16 tile[32][33];
  const int n0 = blockIdx.x * 32, k0 = blockIdx.y * 32;
  const int r = threadIdx.x >> 5, c = threadIdx.x & 31;
#pragma unroll
  for (int i = 0; i < 4; i++)
    tile[r + i * 8][c] = (bf16)in[(size_t)(k0 + r + i * 8) * N + n0 + c];
  __syncthreads();
#pragma unroll
  for (int i = 0; i < 4; i++)
    out[(size_t)(n0 + r + i * 8) * K + k0 + c] = tile[c][r + i * 8];
}

// ---------------- 128x128 bf16 MFMA GEMM, global_load_lds staging (m97) ----
template <int MODE>
__global__ __launch_bounds__(256) void gemm128(const bf16* __restrict__ A,
                                               const bf16* __restrict__ Bt,
                                               const float* __restrict__ bias,
                                               void* __restrict__ o0,
                                               bf16* __restrict__ o1,
                                               f16* __restrict__ o2,
                                               int M, int N, int K) {
  __shared__ __align__(16) bf16 As[128 * 32];
  __shared__ __align__(16) bf16 Bs[128 * 32];
  const int tid = threadIdx.x;
  const int m0 = blockIdx.y * 128, n0 = blockIdx.x * 128;
  const int lane = tid & 63, wv = tid >> 6;
  const int wm = (wv >> 1) * 64, wn = (wv & 1) * 64;
  const int col = lane & 15, quad = lane >> 4;

  floatx4 acc[4][4];
#pragma unroll
  for (int i = 0; i < 4; i++)
#pragma unroll
    for (int j = 0; j < 4; j++) acc[i][j] = (floatx4){0.f, 0.f, 0.f, 0.f};

  const int c0 = tid, c1 = tid + 256;
  const bf16* a0 = A + (size_t)(m0 + (c0 >> 2)) * K + (c0 & 3) * 8;
  const bf16* a1 = A + (size_t)(m0 + (c1 >> 2)) * K + (c1 & 3) * 8;
  const bf16* b0 = Bt + (size_t)(n0 + (c0 >> 2)) * K + (c0 & 3) * 8;
  const bf16* b1 = Bt + (size_t)(n0 + (c1 >> 2)) * K + (c1 & 3) * 8;
  bf16* lA0 = &As[(wv * 64) * 8];
  bf16* lA1 = &As[(wv * 64 + 256) * 8];
  bf16* lB0 = &Bs[(wv * 64) * 8];
  bf16* lB1 = &Bs[(wv * 64 + 256) * 8];

  for (int kt = 0; kt < K; kt += 32) {
    gl_lds16(a0 + kt, lA0);
    gl_lds16(a1 + kt, lA1);
    gl_lds16(b0 + kt, lB0);
    gl_lds16(b1 + kt, lB1);
    __syncthreads();
    bf16x8 afr[4], bg[4];
#pragma unroll
    for (int mb = 0; mb < 4; mb++)
      afr[mb] = *(const bf16x8*)&As[(wm + mb * 16 + col) * 32 + quad * 8];
#pragma unroll
    for (int nb = 0; nb < 4; nb++)
      bg[nb] = *(const bf16x8*)&Bs[(wn + nb * 16 + col) * 32 + quad * 8];
#pragma unroll
    for (int mb = 0; mb < 4; mb++)
#pragma unroll
      for (int nb = 0; nb < 4; nb++)
        acc[mb][nb] = mfma16(afr[mb], bg[nb], acc[mb][nb]);
    __syncthreads();
  }

#pragma unroll
  for (int mb = 0; mb < 4; mb++) {
    const int mg = m0 + wm + mb * 16 + quad * 4;
#pragma unroll
    for (int nb = 0; nb < 4; nb++) {
      const int ng = n0 + wn + nb * 16 + col;
      const float bs = bias[ng];
      if (MODE == 0) {
        const int third = ng >> 10;
        const int nn = ng & 1023;
        const int h = nn >> 6, d = nn & 63;
#pragma unroll
        for (int r = 0; r < 4; r++) {
          const int mm = mg + r;
          const int bb = mm >> 11, t = mm & 2047;
          const float v = acc[mb][nb][r] + bs;
          if (third == 0)
            ((bf16*)o0)[(((size_t)bb * H_ + h) * T_ + t) * D_ + d] = (bf16)v;
          else if (third == 1)
            o1[(((size_t)bb * H_ + h) * T_ + t) * D_ + d] = (bf16)v;
          else
            o2[(((size_t)bb * H_ + h) * D_ + d) * T_ + t] = (f16)v;  // V^T f16
        }
      } else {
#pragma unroll
        for (int r = 0; r < 4; r++)
          ((float*)o0)[(size_t)(mg + r) * N + ng] = acc[mb][nb][r] + bs;
      }
    }
  }
}

// ---------------- flash attention: block = (bh, qtile); 4-way key split ----
// Q,K: [B,H,T,D] bf16; VT: [B,H,D,T] f16; Y: [B,T,C] bf16
// S^T = mfma(A=K, B=Q): C-layout (key=quad*4+r, qrow=col) == B-frag of 16x16x16.
// O^T += mfma16x16x16f16(A=V^T, B=P^T). Static-max softmax => partials add.
__global__ __launch_bounds__(256, 4) void attn(const bf16* __restrict__ Q,
                                               const bf16* __restrict__ Km,
                                               const f16* __restrict__ VT,
                                               bf16* __restrict__ Y) {
  const int tid = threadIdx.x, lane = tid & 63, wv = tid >> 6;
  const int col = lane & 15, quad = lane >> 4;
  // 4096 blocks: xcd = id&7, j = id>>3; bh = ((j&7)<<3)|xcd; qtile = 63-(j>>3)
  const int id = blockIdx.x;
  const int j = id >> 3;
  const int bh = ((j & 7) << 3) | (id & 7);
  const int qtile = 63 - (j >> 3);  // longest blocks dispatch first
  const int b = bh >> 4, h = bh & 15;
  const int qbase = qtile * 32;

  __shared__ __align__(16) floatx4 mbuf[3][8][64];  // 24 KB partial-O
  __shared__ float lbuf[3][2][64];                  // 1.5 KB partial-lsum

  const bf16* kb = Km + (size_t)bh * T_ * D_;
  const f16* vb = VT + (size_t)bh * D_ * T_;

  // Q as B-fragments (n=qrow=col, k=d=quad*8+j)
  bf16x8 qf[2][2];
#pragma unroll
  for (int mq = 0; mq < 2; mq++) {
    const bf16* qp = Q + ((size_t)bh * T_ + qbase + mq * 16 + col) * D_ + quad * 8;
    qf[mq][0] = *(const bf16x8*)qp;
    qf[mq][1] = *(const bf16x8*)(qp + 32);
  }

  floatx4 o[2][4];  // O^T: dim = sub*16 + quad*4 + r, qrow = col
  float lsum[2] = {0.f, 0.f};
#pragma unroll
  for (int mq = 0; mq < 2; mq++)
#pragma unroll
    for (int s = 0; s < 4; s++) o[mq][s] = (floatx4){0.f, 0.f, 0.f, 0.f};

  const float C1 = 0.18033688f;  // 0.125*log2(e)
  const float C2 = 11.541560f;   // 8*log2(e): p = exp2(s*C1 - C2), exact softmax

  // this wave's tiles: kt = wv + 4*i, i in [0, nmine); last == qtile -> masked
  const int nmine = (qtile >= wv) ? ((qtile - wv) >> 2) + 1 : 0;

  auto load_k = [&](int kt, bf16x8 (&ka)[2][2]) {
    const int k0 = kt * 32;
#pragma unroll
    for (int st = 0; st < 2; st++) {
      const bf16* kp = kb + (size_t)(k0 + st * 16 + col) * D_ + quad * 8;
      ka[st][0] = *(const bf16x8*)kp;
      ka[st][1] = *(const bf16x8*)(kp + 32);
    }
  };
  auto compute = [&](int kt, const bf16x8 (&ka)[2][2], bool masked) {
    const int k0 = kt * 32;
    f16x4 va[2][4];
#pragma unroll
    for (int st = 0; st < 2; st++)
#pragma unroll
      for (int sub = 0; sub < 4; sub++)
        va[st][sub] = *(const f16x4*)(vb + (size_t)(sub * 16 + col) * T_ + k0 +
                                      st * 16 + quad * 4);
#pragma unroll
    for (int mq = 0; mq < 2; mq++) {
#pragma unroll
      for (int st = 0; st < 2; st++) {
        if (masked && mq == 0 && st == 1) continue;  // fully masked sub-tile
        floatx4 s = (floatx4){0.f, 0.f, 0.f, 0.f};
        s = mfma16(ka[st][0], qf[mq][0], s);
        s = mfma16(ka[st][1], qf[mq][1], s);
        f16x4 pf;
        float ps = 0.f;
        const bool diag = masked && (mq == st);
#pragma unroll
        for (int r = 0; r < 4; r++) {
          float p = exp2f(fmaf(s[r], C1, -C2));
          if (diag && (quad * 4 + r > col)) p = 0.f;
          ps += p;
          pf[r] = (f16)p;
        }
        lsum[mq] += ps;
#pragma unroll
        for (int sub = 0; sub < 4; sub++)
          o[mq][sub] = mfma_pv(va[st][sub], pf, o[mq][sub]);
      }
    }
  };

  bf16x8 kaA[2][2], kaB[2][2];
  if (nmine > 0) load_k(wv, kaA);
  for (int i = 0; i < nmine;) {
    int kt = wv + 4 * i;
    if (i + 1 < nmine) load_k(kt + 4, kaB);
    compute(kt, kaA, kt == qtile);
    if (++i >= nmine) break;
    kt = wv + 4 * i;
    if (i + 1 < nmine) load_k(kt + 4, kaA);
    compute(kt, kaB, kt == qtile);
    ++i;
  }

  // ---- merge: waves 1..3 dump partials; wave 0 adds + writes ----
  if (wv != 0) {
#pragma unroll
    for (int mq = 0; mq < 2; mq++) {
#pragma unroll
      for (int sub = 0; sub < 4; sub++) mbuf[wv - 1][mq * 4 + sub][lane] = o[mq][sub];
      lbuf[wv - 1][mq][lane] = lsum[mq];
    }
  }
  __syncthreads();
  if (wv == 0) {
#pragma unroll
    for (int w = 0; w < 3; w++)
#pragma unroll
      for (int mq = 0; mq < 2; mq++) {
#pragma unroll
        for (int sub = 0; sub < 4; sub++) o[mq][sub] += mbuf[w][mq * 4 + sub][lane];
        lsum[mq] += lbuf[w][mq][lane];
      }
#pragma unroll
    for (int mq = 0; mq < 2; mq++) {
      lsum[mq] += __shfl_xor(lsum[mq], 16);
      lsum[mq] += __shfl_xor(lsum[mq], 32);
      const float rinv = 1.f / lsum[mq];
      const int qrow = qbase + mq * 16 + col;
#pragma unroll
      for (int sub = 0; sub < 4; sub++) {
        bf16x4 yv;
#pragma unroll
        for (int r = 0; r < 4; r++) yv[r] = (bf16)(o[mq][sub][r] * rinv);
        *(bf16x4*)&Y[((size_t)b * T_ + qrow) * C_ + h * 64 + sub * 16 + quad * 4] = yv;
      }
    }
  }
}

extern "C" void kernel_launch(void* const* d_in, const int* in_sizes, int n_in,
                              void* d_out, int out_size, void* d_ws, size_t ws_size,
                              hipStream_t stream) {
  (void)in_sizes; (void)n_in; (void)out_size; (void)ws_size;
  const float* x      = (const float*)d_in[0];  // [B*T, C]
  const float* w_qkv  = (const float*)d_in[1];  // [C, 3C]
  const float* b_qkv  = (const float*)d_in[2];  // [3C]
  const float* w_proj = (const float*)d_in[3];  // [C, C]
  const float* b_proj = (const float*)d_in[4];  // [C]

  char* ws = (char*)d_ws;
  bf16* wqkv_t  = (bf16*)(ws);                  // [3C, C]   6291456 B
  bf16* wproj_t = (bf16*)(ws + 6291456);        // [C, C]    2097152 B
  bf16* qb      = (bf16*)(ws + 8388608);        // [B,H,T,D] 16777216 B
  bf16* kbuf    = (bf16*)(ws + 25165824);       // [B,H,T,D] 16777216 B
  f16*  vtbuf   = (f16*)(ws + 41943040);        // [B,H,D,T] 16777216 B
  bf16* yb      = (bf16*)(ws + 58720256);       // [B*T, C]  16777216 B
  bf16* xb      = (bf16*)(ws + 58720256);       // aliases yb (dead before attn)

  cvt_bf16<<<8192, 256, 0, stream>>>(x, xb);
  transpose_f32<<<dim3(96, 32), 256, 0, stream>>>(w_qkv, wqkv_t, 1024, 3072);
  transpose_f32<<<dim3(32, 32), 256, 0, stream>>>(w_proj, wproj_t, 1024, 1024);
  gemm128<0><<<dim3(24, 64), 256, 0, stream>>>(xb, wqkv_t, b_qkv, qb, kbuf, vtbuf,
                                               8192, 3072, 1024);
  attn<<<dim3(4096), 256, 0, stream>>>(qb, kbuf, vtbuf, yb);
  gemm128<1><<<dim3(8, 64), 256, 0, stream>>>(yb, wproj_t, b_proj, d_out, nullptr,
                                              nullptr, 8192, 1024, 1024);
}

// Round 7
// 401.084 us; speedup vs baseline: 1.4913x; 1.4913x over previous
//
#include <hip/hip_runtime.h>
#include <hip/hip_bf16.h>
#include <stdint.h>

// Problem constants: B=4, T=2048, C=1024, H=16, D=64. Inputs f32, output f32.
#define B_ 4
#define T_ 2048
#define C_ 1024
#define H_ 16
#define D_ 64

typedef __bf16 bf16;
typedef _Float16 f16;
typedef __attribute__((ext_vector_type(8))) __bf16 bf16x8;
typedef __attribute__((ext_vector_type(4))) __bf16 bf16x4;
typedef __attribute__((ext_vector_type(4))) _Float16 f16x4;
typedef __attribute__((ext_vector_type(4))) float floatx4;

__device__ __forceinline__ floatx4 mfma16(bf16x8 a, bf16x8 b, floatx4 c) {
  return __builtin_amdgcn_mfma_f32_16x16x32_bf16(a, b, c, 0, 0, 0);
}
__device__ __forceinline__ floatx4 mfma_pv(f16x4 a, f16x4 b, floatx4 c) {
  return __builtin_amdgcn_mfma_f32_16x16x16f16(a, b, c, 0, 0, 0);
}

__device__ __forceinline__ void gl_lds16(const void* g, void* l) {
  __builtin_amdgcn_global_load_lds(
      (__attribute__((address_space(1))) uint32_t*)g,
      (__attribute__((address_space(3))) uint32_t*)l, 16, 0, 0);
}

// ---------------- f32 -> bf16 bulk convert ----------------
__global__ __launch_bounds__(256) void cvt_bf16(const float* __restrict__ in,
                                                bf16* __restrict__ out) {
  const size_t i = ((size_t)blockIdx.x * 256 + threadIdx.x) * 4;
  const floatx4 v = *(const floatx4*)(in + i);
  bf16x4 r;
#pragma unroll
  for (int j = 0; j < 4; j++) r[j] = (bf16)v[j];
  *(bf16x4*)(out + i) = r;
}

// ---------------- transpose: in[K][N] f32 -> out[N][K] bf16 ----------------
__global__ __launch_bounds__(256) void transpose_f32(const float* __restrict__ in,
                                                     bf16* __restrict__ out,
                                                     int K, int N) {
  __shared__ bf16 tile[32][33];
  const int n0 = blockIdx.x * 32, k0 = blockIdx.y * 32;
  const int r = threadIdx.x >> 5, c = threadIdx.x & 31;
#pragma unroll
  for (int i = 0; i < 4; i++)
    tile[r + i * 8][c] = (bf16)in[(size_t)(k0 + r + i * 8) * N + n0 + c];
  __syncthreads();
#pragma unroll
  for (int i = 0; i < 4; i++)
    out[(size_t)(n0 + r + i * 8) * K + k0 + c] = tile[c][r + i * 8];
}

// ---------------- 128x128 bf16 MFMA GEMM, global_load_lds staging (m97) ----
template <int MODE>
__global__ __launch_bounds__(256) void gemm128(const bf16* __restrict__ A,
                                               const bf16* __restrict__ Bt,
                                               const float* __restrict__ bias,
                                               void* __restrict__ o0,
                                               bf16* __restrict__ o1,
                                               f16* __restrict__ o2,
                                               int M, int N, int K) {
  __shared__ __align__(16) bf16 As[128 * 32];
  __shared__ __align__(16) bf16 Bs[128 * 32];
  const int tid = threadIdx.x;
  const int m0 = blockIdx.y * 128, n0 = blockIdx.x * 128;
  const int lane = tid & 63, wv = tid >> 6;
  const int wm = (wv >> 1) * 64, wn = (wv & 1) * 64;
  const int col = lane & 15, quad = lane >> 4;

  floatx4 acc[4][4];
#pragma unroll
  for (int i = 0; i < 4; i++)
#pragma unroll
    for (int j = 0; j < 4; j++) acc[i][j] = (floatx4){0.f, 0.f, 0.f, 0.f};

  const int c0 = tid, c1 = tid + 256;
  const bf16* a0 = A + (size_t)(m0 + (c0 >> 2)) * K + (c0 & 3) * 8;
  const bf16* a1 = A + (size_t)(m0 + (c1 >> 2)) * K + (c1 & 3) * 8;
  const bf16* b0 = Bt + (size_t)(n0 + (c0 >> 2)) * K + (c0 & 3) * 8;
  const bf16* b1 = Bt + (size_t)(n0 + (c1 >> 2)) * K + (c1 & 3) * 8;
  bf16* lA0 = &As[(wv * 64) * 8];
  bf16* lA1 = &As[(wv * 64 + 256) * 8];
  bf16* lB0 = &Bs[(wv * 64) * 8];
  bf16* lB1 = &Bs[(wv * 64 + 256) * 8];

  for (int kt = 0; kt < K; kt += 32) {
    gl_lds16(a0 + kt, lA0);
    gl_lds16(a1 + kt, lA1);
    gl_lds16(b0 + kt, lB0);
    gl_lds16(b1 + kt, lB1);
    __syncthreads();
    bf16x8 afr[4], bg[4];
#pragma unroll
    for (int mb = 0; mb < 4; mb++)
      afr[mb] = *(const bf16x8*)&As[(wm + mb * 16 + col) * 32 + quad * 8];
#pragma unroll
    for (int nb = 0; nb < 4; nb++)
      bg[nb] = *(const bf16x8*)&Bs[(wn + nb * 16 + col) * 32 + quad * 8];
#pragma unroll
    for (int mb = 0; mb < 4; mb++)
#pragma unroll
      for (int nb = 0; nb < 4; nb++)
        acc[mb][nb] = mfma16(afr[mb], bg[nb], acc[mb][nb]);
    __syncthreads();
  }

#pragma unroll
  for (int mb = 0; mb < 4; mb++) {
    const int mg = m0 + wm + mb * 16 + quad * 4;
#pragma unroll
    for (int nb = 0; nb < 4; nb++) {
      const int ng = n0 + wn + nb * 16 + col;
      const float bs = bias[ng];
      if (MODE == 0) {
        const int third = ng >> 10;
        const int nn = ng & 1023;
        const int h = nn >> 6, d = nn & 63;
#pragma unroll
        for (int r = 0; r < 4; r++) {
          const int mm = mg + r;
          const int bb = mm >> 11, t = mm & 2047;
          const float v = acc[mb][nb][r] + bs;
          if (third == 0)
            ((bf16*)o0)[(((size_t)bb * H_ + h) * T_ + t) * D_ + d] = (bf16)v;
          else if (third == 1)
            o1[(((size_t)bb * H_ + h) * T_ + t) * D_ + d] = (bf16)v;
          else
            o2[(((size_t)bb * H_ + h) * D_ + d) * T_ + t] = (f16)v;  // V^T f16
        }
      } else {
#pragma unroll
        for (int r = 0; r < 4; r++)
          ((float*)o0)[(size_t)(mg + r) * N + ng] = acc[mb][nb][r] + bs;
      }
    }
  }
}

// ---------------- flash attention: block = (bh, qtile); 4-way key split ----
// Q,K: [B,H,T,D] bf16; VT: [B,H,D,T] f16; Y: [B,T,C] bf16
// S^T = mfma(A=K, B=Q): C-layout (key=quad*4+r, qrow=col) == B-frag of 16x16x16.
// O^T += mfma16x16x16f16(A=V^T, B=P^T). Static-max softmax => partials add.
// NO register prefetch: round-6's kaA/kaB double-buffer spilled to scratch
// (512 MB WRITE_SIZE); latency hiding comes from ~14 resident waves/CU instead.
__global__ __launch_bounds__(256, 4) void attn(const bf16* __restrict__ Q,
                                               const bf16* __restrict__ Km,
                                               const f16* __restrict__ VT,
                                               bf16* __restrict__ Y) {
  const int tid = threadIdx.x, lane = tid & 63, wv = tid >> 6;
  const int col = lane & 15, quad = lane >> 4;
  // 4096 blocks: xcd = id&7, j = id>>3; bh = ((j&7)<<3)|xcd; qtile = 63-(j>>3)
  const int id = blockIdx.x;
  const int j = id >> 3;
  const int bh = ((j & 7) << 3) | (id & 7);
  const int qtile = 63 - (j >> 3);  // longest blocks dispatch first
  const int b = bh >> 4, h = bh & 15;
  const int qbase = qtile * 32;

  __shared__ __align__(16) floatx4 mbuf[3][8][64];  // 24 KB partial-O
  __shared__ float lbuf[3][2][64];                  // 1.5 KB partial-lsum

  const bf16* kb = Km + (size_t)bh * T_ * D_;
  const f16* vb = VT + (size_t)bh * D_ * T_;

  // Q as B-fragments (n=qrow=col, k=d=quad*8+j)
  bf16x8 qf[2][2];
#pragma unroll
  for (int mq = 0; mq < 2; mq++) {
    const bf16* qp = Q + ((size_t)bh * T_ + qbase + mq * 16 + col) * D_ + quad * 8;
    qf[mq][0] = *(const bf16x8*)qp;
    qf[mq][1] = *(const bf16x8*)(qp + 32);
  }

  floatx4 o[2][4];  // O^T: dim = sub*16 + quad*4 + r, qrow = col
  float lsum[2] = {0.f, 0.f};
#pragma unroll
  for (int mq = 0; mq < 2; mq++)
#pragma unroll
    for (int s = 0; s < 4; s++) o[mq][s] = (floatx4){0.f, 0.f, 0.f, 0.f};

  const float C1 = 0.18033688f;  // 0.125*log2(e)
  const float C2 = 11.541560f;   // 8*log2(e): p = exp2(s*C1 - C2), exact softmax

  // this wave's tiles: kt = wv + 4*i; last one (== qtile) is the masked diagonal
  const int nmine = (qtile >= wv) ? ((qtile - wv) >> 2) + 1 : 0;

  for (int i = 0; i < nmine; i++) {
    const int kt = wv + 4 * i;
    const int k0 = kt * 32;
    const bool masked = (kt == qtile);
    bf16x8 ka[2][2];
#pragma unroll
    for (int st = 0; st < 2; st++) {
      const bf16* kp = kb + (size_t)(k0 + st * 16 + col) * D_ + quad * 8;
      ka[st][0] = *(const bf16x8*)kp;
      ka[st][1] = *(const bf16x8*)(kp + 32);
    }
#pragma unroll
    for (int st = 0; st < 2; st++) {
      f16x4 va[4];
#pragma unroll
      for (int sub = 0; sub < 4; sub++)
        va[sub] = *(const f16x4*)(vb + (size_t)(sub * 16 + col) * T_ + k0 +
                                  st * 16 + quad * 4);
#pragma unroll
      for (int mq = 0; mq < 2; mq++) {
        if (masked && mq == 0 && st == 1) continue;  // fully masked sub-tile
        floatx4 s = (floatx4){0.f, 0.f, 0.f, 0.f};
        s = mfma16(ka[st][0], qf[mq][0], s);
        s = mfma16(ka[st][1], qf[mq][1], s);
        f16x4 pf;
        float ps = 0.f;
        const bool diag = masked && (mq == st);
#pragma unroll
        for (int r = 0; r < 4; r++) {
          float p = exp2f(fmaf(s[r], C1, -C2));
          if (diag && (quad * 4 + r > col)) p = 0.f;
          ps += p;
          pf[r] = (f16)p;
        }
        lsum[mq] += ps;
#pragma unroll
        for (int sub = 0; sub < 4; sub++)
          o[mq][sub] = mfma_pv(va[sub], pf, o[mq][sub]);
      }
    }
  }

  // ---- merge: waves 1..3 dump partials; wave 0 adds + writes ----
  if (wv != 0) {
#pragma unroll
    for (int mq = 0; mq < 2; mq++) {
#pragma unroll
      for (int sub = 0; sub < 4; sub++) mbuf[wv - 1][mq * 4 + sub][lane] = o[mq][sub];
      lbuf[wv - 1][mq][lane] = lsum[mq];
    }
  }
  __syncthreads();
  if (wv == 0) {
#pragma unroll
    for (int w = 0; w < 3; w++)
#pragma unroll
      for (int mq = 0; mq < 2; mq++) {
#pragma unroll
        for (int sub = 0; sub < 4; sub++) o[mq][sub] += mbuf[w][mq * 4 + sub][lane];
        lsum[mq] += lbuf[w][mq][lane];
      }
#pragma unroll
    for (int mq = 0; mq < 2; mq++) {
      lsum[mq] += __shfl_xor(lsum[mq], 16);
      lsum[mq] += __shfl_xor(lsum[mq], 32);
      const float rinv = 1.f / lsum[mq];
      const int qrow = qbase + mq * 16 + col;
#pragma unroll
      for (int sub = 0; sub < 4; sub++) {
        bf16x4 yv;
#pragma unroll
        for (int r = 0; r < 4; r++) yv[r] = (bf16)(o[mq][sub][r] * rinv);
        *(bf16x4*)&Y[((size_t)b * T_ + qrow) * C_ + h * 64 + sub * 16 + quad * 4] = yv;
      }
    }
  }
}

extern "C" void kernel_launch(void* const* d_in, const int* in_sizes, int n_in,
                              void* d_out, int out_size, void* d_ws, size_t ws_size,
                              hipStream_t stream) {
  (void)in_sizes; (void)n_in; (void)out_size; (void)ws_size;
  const float* x      = (const float*)d_in[0];  // [B*T, C]
  const float* w_qkv  = (const float*)d_in[1];  // [C, 3C]
  const float* b_qkv  = (const float*)d_in[2];  // [3C]
  const float* w_proj = (const float*)d_in[3];  // [C, C]
  const float* b_proj = (const float*)d_in[4];  // [C]

  char* ws = (char*)d_ws;
  bf16* wqkv_t  = (bf16*)(ws);                  // [3C, C]   6291456 B
  bf16* wproj_t = (bf16*)(ws + 6291456);        // [C, C]    2097152 B
  bf16* qb      = (bf16*)(ws + 8388608);        // [B,H,T,D] 16777216 B
  bf16* kbuf    = (bf16*)(ws + 25165824);       // [B,H,T,D] 16777216 B
  f16*  vtbuf   = (f16*)(ws + 41943040);        // [B,H,D,T] 16777216 B
  bf16* yb      = (bf16*)(ws + 58720256);       // [B*T, C]  16777216 B
  bf16* xb      = (bf16*)(ws + 58720256);       // aliases yb (dead before attn)

  cvt_bf16<<<8192, 256, 0, stream>>>(x, xb);
  transpose_f32<<<dim3(96, 32), 256, 0, stream>>>(w_qkv, wqkv_t, 1024, 3072);
  transpose_f32<<<dim3(32, 32), 256, 0, stream>>>(w_proj, wproj_t, 1024, 1024);
  gemm128<0><<<dim3(24, 64), 256, 0, stream>>>(xb, wqkv_t, b_qkv, qb, kbuf, vtbuf,
                                               8192, 3072, 1024);
  attn<<<dim3(4096), 256, 0, stream>>>(qb, kbuf, vtbuf, yb);
  gemm128<1><<<dim3(8, 64), 256, 0, stream>>>(yb, wproj_t, b_proj, d_out, nullptr,
                                              nullptr, 8192, 1024, 1024);
}

// Round 8
// 271.913 us; speedup vs baseline: 2.1997x; 1.4750x over previous
//
#include <hip/hip_runtime.h>
#include <hip/hip_bf16.h>
#include <stdint.h>

// Problem constants: B=4, T=2048, C=1024, H=16, D=64. Inputs f32, output f32.
#define B_ 4
#define T_ 2048
#define C_ 1024
#define H_ 16
#define D_ 64

typedef __bf16 bf16;
typedef _Float16 f16;
typedef __attribute__((ext_vector_type(8))) __bf16 bf16x8;
typedef __attribute__((ext_vector_type(4))) __bf16 bf16x4;
typedef __attribute__((ext_vector_type(4))) _Float16 f16x4;
typedef __attribute__((ext_vector_type(8))) _Float16 f16x8;
typedef __attribute__((ext_vector_type(4))) float floatx4;

__device__ __forceinline__ floatx4 mfma16(bf16x8 a, bf16x8 b, floatx4 c) {
  return __builtin_amdgcn_mfma_f32_16x16x32_bf16(a, b, c, 0, 0, 0);
}
__device__ __forceinline__ floatx4 mfma_pv(f16x4 a, f16x4 b, floatx4 c) {
  return __builtin_amdgcn_mfma_f32_16x16x16f16(a, b, c, 0, 0, 0);
}

__device__ __forceinline__ void gl_lds16(const void* g, void* l) {
  __builtin_amdgcn_global_load_lds(
      (__attribute__((address_space(1))) uint32_t*)g,
      (__attribute__((address_space(3))) uint32_t*)l, 16, 0, 0);
}

// ---------------- f32 -> bf16 bulk convert ----------------
__global__ __launch_bounds__(256) void cvt_bf16(const float* __restrict__ in,
                                                bf16* __restrict__ out) {
  const size_t i = ((size_t)blockIdx.x * 256 + threadIdx.x) * 4;
  const floatx4 v = *(const floatx4*)(in + i);
  bf16x4 r;
#pragma unroll
  for (int j = 0; j < 4; j++) r[j] = (bf16)v[j];
  *(bf16x4*)(out + i) = r;
}

// ---------------- transpose: in[K][N] f32 -> out[N][K] bf16 ----------------
__global__ __launch_bounds__(256) void transpose_f32(const float* __restrict__ in,
                                                     bf16* __restrict__ out,
                                                     int K, int N) {
  __shared__ bf16 tile[32][33];
  const int n0 = blockIdx.x * 32, k0 = blockIdx.y * 32;
  const int r = threadIdx.x >> 5, c = threadIdx.x & 31;
#pragma unroll
  for (int i = 0; i < 4; i++)
    tile[r + i * 8][c] = (bf16)in[(size_t)(k0 + r + i * 8) * N + n0 + c];
  __syncthreads();
#pragma unroll
  for (int i = 0; i < 4; i++)
    out[(size_t)(n0 + r + i * 8) * K + k0 + c] = tile[c][r + i * 8];
}

// ---------------- 128x128 bf16 MFMA GEMM, global_load_lds staging (m97) ----
// MODE 0 scatters K/V into FRAGMENT-MAJOR layouts for attn:
//   Kp: [bh][kt(64)][st(2)][half(2)][lane(64)][8 bf16]   (b128 @ base+lane*16)
//   Vp: [bh][kt(64)][sub(4)][lane(64)][st0 f16x4|st1 f16x4]
template <int MODE>
__global__ __launch_bounds__(256) void gemm128(const bf16* __restrict__ A,
                                               const bf16* __restrict__ Bt,
                                               const float* __restrict__ bias,
                                               void* __restrict__ o0,
                                               bf16* __restrict__ o1,
                                               f16* __restrict__ o2,
                                               int M, int N, int K) {
  __shared__ __align__(16) bf16 As[128 * 32];
  __shared__ __align__(16) bf16 Bs[128 * 32];
  const int tid = threadIdx.x;
  const int m0 = blockIdx.y * 128, n0 = blockIdx.x * 128;
  const int lane = tid & 63, wv = tid >> 6;
  const int wm = (wv >> 1) * 64, wn = (wv & 1) * 64;
  const int col = lane & 15, quad = lane >> 4;

  floatx4 acc[4][4];
#pragma unroll
  for (int i = 0; i < 4; i++)
#pragma unroll
    for (int j = 0; j < 4; j++) acc[i][j] = (floatx4){0.f, 0.f, 0.f, 0.f};

  const int c0 = tid, c1 = tid + 256;
  const bf16* a0 = A + (size_t)(m0 + (c0 >> 2)) * K + (c0 & 3) * 8;
  const bf16* a1 = A + (size_t)(m0 + (c1 >> 2)) * K + (c1 & 3) * 8;
  const bf16* b0 = Bt + (size_t)(n0 + (c0 >> 2)) * K + (c0 & 3) * 8;
  const bf16* b1 = Bt + (size_t)(n0 + (c1 >> 2)) * K + (c1 & 3) * 8;
  bf16* lA0 = &As[(wv * 64) * 8];
  bf16* lA1 = &As[(wv * 64 + 256) * 8];
  bf16* lB0 = &Bs[(wv * 64) * 8];
  bf16* lB1 = &Bs[(wv * 64 + 256) * 8];

  for (int kt = 0; kt < K; kt += 32) {
    gl_lds16(a0 + kt, lA0);
    gl_lds16(a1 + kt, lA1);
    gl_lds16(b0 + kt, lB0);
    gl_lds16(b1 + kt, lB1);
    __syncthreads();
    bf16x8 afr[4], bg[4];
#pragma unroll
    for (int mb = 0; mb < 4; mb++)
      afr[mb] = *(const bf16x8*)&As[(wm + mb * 16 + col) * 32 + quad * 8];
#pragma unroll
    for (int nb = 0; nb < 4; nb++)
      bg[nb] = *(const bf16x8*)&Bs[(wn + nb * 16 + col) * 32 + quad * 8];
#pragma unroll
    for (int mb = 0; mb < 4; mb++)
#pragma unroll
      for (int nb = 0; nb < 4; nb++)
        acc[mb][nb] = mfma16(afr[mb], bg[nb], acc[mb][nb]);
    __syncthreads();
  }

#pragma unroll
  for (int mb = 0; mb < 4; mb++) {
    const int mg = m0 + wm + mb * 16 + quad * 4;
#pragma unroll
    for (int nb = 0; nb < 4; nb++) {
      const int ng = n0 + wn + nb * 16 + col;
      const float bs = bias[ng];
      if (MODE == 0) {
        const int third = ng >> 10;
        const int nn = ng & 1023;
        const int h = nn >> 6, d = nn & 63;
#pragma unroll
        for (int r = 0; r < 4; r++) {
          const int mm = mg + r;
          const int bb = mm >> 11, t = mm & 2047;
          const float v = acc[mb][nb][r] + bs;
          const size_t bh = (size_t)bb * H_ + h;
          if (third == 0) {
            ((bf16*)o0)[(bh * T_ + t) * D_ + d] = (bf16)v;
          } else if (third == 1) {
            // K fragment-major: [bh][t>>5][(t>>4)&1][d>>5][lane2][d&7]
            const int lane2 = (t & 15) | (((d >> 3) & 3) << 4);
            const size_t idx =
                ((((bh * 64 + (t >> 5)) * 2 + ((t >> 4) & 1)) * 2 + (d >> 5)) * 64 +
                 lane2) * 8 + (d & 7);
            o1[idx] = (bf16)v;
          } else {
            // V fragment-major: [bh][t>>5][d>>4][lane2][((t>>4)&1)*4 + (t&3)]
            const int lane2 = (d & 15) | (((t >> 2) & 3) << 4);
            const size_t idx =
                (((bh * 64 + (t >> 5)) * 4 + (d >> 4)) * 64 + lane2) * 8 +
                ((t >> 4) & 1) * 4 + (t & 3);
            o2[idx] = (f16)v;
          }
        }
      } else {
#pragma unroll
        for (int r = 0; r < 4; r++)
          ((float*)o0)[(size_t)(mg + r) * N + ng] = acc[mb][nb][r] + bs;
      }
    }
  }
}

// ---------------- flash attention: block = (bh, qtile); 4-way key split ----
// Q: [B,H,T,D] bf16; Kp/Vp: fragment-major (see gemm128); Y: [B,T,C] bf16
// All per-tile loads are lane-contiguous b128 (coalesced 1KB/instr), batched
// up front for MLP (round-7's VGPR=56 showed the compiler serialized loads).
__global__ __launch_bounds__(256, 4) void attn(const bf16* __restrict__ Q,
                                               const bf16* __restrict__ Kp,
                                               const f16* __restrict__ Vp,
                                               bf16* __restrict__ Y) {
  const int tid = threadIdx.x, lane = tid & 63, wv = tid >> 6;
  const int col = lane & 15, quad = lane >> 4;
  // 4096 blocks: xcd = id&7, j = id>>3; bh = ((j&7)<<3)|xcd; qtile = 63-(j>>3)
  const int id = blockIdx.x;
  const int j = id >> 3;
  const int bh = ((j & 7) << 3) | (id & 7);
  const int qtile = 63 - (j >> 3);  // longest blocks dispatch first
  const int b = bh >> 4, h = bh & 15;
  const int qbase = qtile * 32;

  __shared__ __align__(16) floatx4 mbuf[3][8][64];  // 24 KB partial-O
  __shared__ float lbuf[3][2][64];                  // 1.5 KB partial-lsum

  // Q as B-fragments (n=qrow=col, k=d=quad*8+j)
  bf16x8 qf[2][2];
#pragma unroll
  for (int mq = 0; mq < 2; mq++) {
    const bf16* qp = Q + ((size_t)bh * T_ + qbase + mq * 16 + col) * D_ + quad * 8;
    qf[mq][0] = *(const bf16x8*)qp;
    qf[mq][1] = *(const bf16x8*)(qp + 32);
  }

  floatx4 o[2][4];  // O^T: dim = sub*16 + quad*4 + r, qrow = col
  float lsum[2] = {0.f, 0.f};
#pragma unroll
  for (int mq = 0; mq < 2; mq++)
#pragma unroll
    for (int s = 0; s < 4; s++) o[mq][s] = (floatx4){0.f, 0.f, 0.f, 0.f};

  const float C1 = 0.18033688f;  // 0.125*log2(e)
  const float C2 = 11.541560f;   // 8*log2(e): p = exp2(s*C1 - C2), exact softmax

  const int nmine = (qtile >= wv) ? ((qtile - wv) >> 2) + 1 : 0;

  for (int i = 0; i < nmine; i++) {
    const int kt = wv + 4 * i;
    const bool masked = (kt == qtile);
    // ---- batched, coalesced fragment loads (8x b128 @ base+lane*16) ----
    const bf16* kbase = Kp + ((size_t)bh * 64 + kt) * 2048 + lane * 8;
    const f16* vbase = Vp + ((size_t)bh * 64 + kt) * 2048 + lane * 8;
    bf16x8 ka[2][2];
    ka[0][0] = *(const bf16x8*)(kbase);
    ka[0][1] = *(const bf16x8*)(kbase + 512);
    ka[1][0] = *(const bf16x8*)(kbase + 1024);
    ka[1][1] = *(const bf16x8*)(kbase + 1536);
    f16x8 vv[4];
#pragma unroll
    for (int sub = 0; sub < 4; sub++) vv[sub] = *(const f16x8*)(vbase + sub * 512);

#pragma unroll
    for (int st = 0; st < 2; st++) {
#pragma unroll
      for (int mq = 0; mq < 2; mq++) {
        if (masked && mq == 0 && st == 1) continue;  // fully masked sub-tile
        floatx4 s = (floatx4){0.f, 0.f, 0.f, 0.f};
        s = mfma16(ka[st][0], qf[mq][0], s);
        s = mfma16(ka[st][1], qf[mq][1], s);
        f16x4 pf;
        float ps = 0.f;
        const bool diag = masked && (mq == st);
#pragma unroll
        for (int r = 0; r < 4; r++) {
          float p = exp2f(fmaf(s[r], C1, -C2));
          if (diag && (quad * 4 + r > col)) p = 0.f;
          ps += p;
          pf[r] = (f16)p;
        }
        lsum[mq] += ps;
#pragma unroll
        for (int sub = 0; sub < 4; sub++) {
          f16x4 va;
#pragma unroll
          for (int jj = 0; jj < 4; jj++) va[jj] = vv[sub][st * 4 + jj];
          o[mq][sub] = mfma_pv(va, pf, o[mq][sub]);
        }
      }
    }
  }

  // ---- merge: waves 1..3 dump partials; wave 0 adds + writes ----
  if (wv != 0) {
#pragma unroll
    for (int mq = 0; mq < 2; mq++) {
#pragma unroll
      for (int sub = 0; sub < 4; sub++) mbuf[wv - 1][mq * 4 + sub][lane] = o[mq][sub];
      lbuf[wv - 1][mq][lane] = lsum[mq];
    }
  }
  __syncthreads();
  if (wv == 0) {
#pragma unroll
    for (int w = 0; w < 3; w++)
#pragma unroll
      for (int mq = 0; mq < 2; mq++) {
#pragma unroll
        for (int sub = 0; sub < 4; sub++) o[mq][sub] += mbuf[w][mq * 4 + sub][lane];
        lsum[mq] += lbuf[w][mq][lane];
      }
#pragma unroll
    for (int mq = 0; mq < 2; mq++) {
      lsum[mq] += __shfl_xor(lsum[mq], 16);
      lsum[mq] += __shfl_xor(lsum[mq], 32);
      const float rinv = 1.f / lsum[mq];
      const int qrow = qbase + mq * 16 + col;
#pragma unroll
      for (int sub = 0; sub < 4; sub++) {
        bf16x4 yv;
#pragma unroll
        for (int r = 0; r < 4; r++) yv[r] = (bf16)(o[mq][sub][r] * rinv);
        *(bf16x4*)&Y[((size_t)b * T_ + qrow) * C_ + h * 64 + sub * 16 + quad * 4] = yv;
      }
    }
  }
}

extern "C" void kernel_launch(void* const* d_in, const int* in_sizes, int n_in,
                              void* d_out, int out_size, void* d_ws, size_t ws_size,
                              hipStream_t stream) {
  (void)in_sizes; (void)n_in; (void)out_size; (void)ws_size;
  const float* x      = (const float*)d_in[0];  // [B*T, C]
  const float* w_qkv  = (const float*)d_in[1];  // [C, 3C]
  const float* b_qkv  = (const float*)d_in[2];  // [3C]
  const float* w_proj = (const float*)d_in[3];  // [C, C]
  const float* b_proj = (const float*)d_in[4];  // [C]

  char* ws = (char*)d_ws;
  bf16* wqkv_t  = (bf16*)(ws);                  // [3C, C]   6291456 B
  bf16* wproj_t = (bf16*)(ws + 6291456);        // [C, C]    2097152 B
  bf16* qb      = (bf16*)(ws + 8388608);        // [B,H,T,D] 16777216 B
  bf16* kbuf    = (bf16*)(ws + 25165824);       // K frag-major 16777216 B
  f16*  vtbuf   = (f16*)(ws + 41943040);        // V frag-major 16777216 B
  bf16* yb      = (bf16*)(ws + 58720256);       // [B*T, C]  16777216 B
  bf16* xb      = (bf16*)(ws + 58720256);       // aliases yb (dead before attn)

  cvt_bf16<<<8192, 256, 0, stream>>>(x, xb);
  transpose_f32<<<dim3(96, 32), 256, 0, stream>>>(w_qkv, wqkv_t, 1024, 3072);
  transpose_f32<<<dim3(32, 32), 256, 0, stream>>>(w_proj, wproj_t, 1024, 1024);
  gemm128<0><<<dim3(24, 64), 256, 0, stream>>>(xb, wqkv_t, b_qkv, qb, kbuf, vtbuf,
                                               8192, 3072, 1024);
  attn<<<dim3(4096), 256, 0, stream>>>(qb, kbuf, vtbuf, yb);
  gemm128<1><<<dim3(8, 64), 256, 0, stream>>>(yb, wproj_t, b_proj, d_out, nullptr,
                                              nullptr, 8192, 1024, 1024);
}

// Round 9
// 258.227 us; speedup vs baseline: 2.3163x; 1.0530x over previous
//
#include <hip/hip_runtime.h>
#include <hip/hip_bf16.h>
#include <stdint.h>

// Problem constants: B=4, T=2048, C=1024, H=16, D=64. Inputs f32, output f32.
#define B_ 4
#define T_ 2048
#define C_ 1024
#define H_ 16
#define D_ 64

typedef __bf16 bf16;
typedef _Float16 f16;
typedef __attribute__((ext_vector_type(8))) __bf16 bf16x8;
typedef __attribute__((ext_vector_type(4))) __bf16 bf16x4;
typedef __attribute__((ext_vector_type(4))) _Float16 f16x4;
typedef __attribute__((ext_vector_type(8))) _Float16 f16x8;
typedef __attribute__((ext_vector_type(4))) float floatx4;

__device__ __forceinline__ floatx4 mfma16(bf16x8 a, bf16x8 b, floatx4 c) {
  return __builtin_amdgcn_mfma_f32_16x16x32_bf16(a, b, c, 0, 0, 0);
}
__device__ __forceinline__ floatx4 mfma_pv(f16x4 a, f16x4 b, floatx4 c) {
  return __builtin_amdgcn_mfma_f32_16x16x16f16(a, b, c, 0, 0, 0);
}

__device__ __forceinline__ void gl_lds16(const void* g, void* l) {
  __builtin_amdgcn_global_load_lds(
      (__attribute__((address_space(1))) uint32_t*)g,
      (__attribute__((address_space(3))) uint32_t*)l, 16, 0, 0);
}

// ---------------- f32 -> bf16 bulk convert ----------------
__global__ __launch_bounds__(256) void cvt_bf16(const float* __restrict__ in,
                                                bf16* __restrict__ out) {
  const size_t i = ((size_t)blockIdx.x * 256 + threadIdx.x) * 4;
  const floatx4 v = *(const floatx4*)(in + i);
  bf16x4 r;
#pragma unroll
  for (int j = 0; j < 4; j++) r[j] = (bf16)v[j];
  *(bf16x4*)(out + i) = r;
}

// ---------------- transpose: in[K][N] f32 -> out[N][K] bf16 ----------------
__global__ __launch_bounds__(256) void transpose_f32(const float* __restrict__ in,
                                                     bf16* __restrict__ out,
                                                     int K, int N) {
  __shared__ bf16 tile[32][33];
  const int n0 = blockIdx.x * 32, k0 = blockIdx.y * 32;
  const int r = threadIdx.x >> 5, c = threadIdx.x & 31;
#pragma unroll
  for (int i = 0; i < 4; i++)
    tile[r + i * 8][c] = (bf16)in[(size_t)(k0 + r + i * 8) * N + n0 + c];
  __syncthreads();
#pragma unroll
  for (int i = 0; i < 4; i++)
    out[(size_t)(n0 + r + i * 8) * K + k0 + c] = tile[c][r + i * 8];
}

// ---------------- 128x128 bf16 MFMA GEMM, BK=64 (two half-buffers) ----------
// C[M,N] = A[M,K] @ Bt[N,K]^T
// MODE 0 (QKV, SWAPPED orientation): A=wqkv_t rows=channels (M=3072),
//   Bt=xb rows=tokens (N=8192), bias indexed by CHANNEL (row).
//   Whole blocks map to one third (Q/K/V) -> uniform epilogue, packed stores.
//   Kp: [bh][kt(64)][st(2)][half(2)][lane(64)][8 bf16]
//   Vp: [bh][kt(64)][sub(4)][lane(64)][st0 f16x4|st1 f16x4]
// MODE 1 (proj): A=yb rows=tokens, bias by column, f32 row-major out.
template <int MODE>
__global__ __launch_bounds__(256) void gemm128(const bf16* __restrict__ A,
                                               const bf16* __restrict__ Bt,
                                               const float* __restrict__ bias,
                                               void* __restrict__ o0,
                                               bf16* __restrict__ o1,
                                               f16* __restrict__ o2,
                                               int M, int N, int K) {
  __shared__ __align__(16) bf16 As[2][128 * 32];
  __shared__ __align__(16) bf16 Bs[2][128 * 32];
  const int tid = threadIdx.x;
  const int m0 = blockIdx.y * 128, n0 = blockIdx.x * 128;
  const int lane = tid & 63, wv = tid >> 6;
  const int wm = (wv >> 1) * 64, wn = (wv & 1) * 64;
  const int col = lane & 15, quad = lane >> 4;

  floatx4 acc[4][4];
#pragma unroll
  for (int i = 0; i < 4; i++)
#pragma unroll
    for (int j = 0; j < 4; j++) acc[i][j] = (floatx4){0.f, 0.f, 0.f, 0.f};

  const int c0 = tid, c1 = tid + 256;
  const bf16* a0 = A + (size_t)(m0 + (c0 >> 2)) * K + (c0 & 3) * 8;
  const bf16* a1 = A + (size_t)(m0 + (c1 >> 2)) * K + (c1 & 3) * 8;
  const bf16* b0 = Bt + (size_t)(n0 + (c0 >> 2)) * K + (c0 & 3) * 8;
  const bf16* b1 = Bt + (size_t)(n0 + (c1 >> 2)) * K + (c1 & 3) * 8;

  for (int kt = 0; kt < K; kt += 64) {
#pragma unroll
    for (int hf = 0; hf < 2; hf++) {
      const int ko = kt + hf * 32;
      gl_lds16(a0 + ko, &As[hf][(wv * 64) * 8]);
      gl_lds16(a1 + ko, &As[hf][(wv * 64 + 256) * 8]);
      gl_lds16(b0 + ko, &Bs[hf][(wv * 64) * 8]);
      gl_lds16(b1 + ko, &Bs[hf][(wv * 64 + 256) * 8]);
    }
    __syncthreads();
#pragma unroll
    for (int hf = 0; hf < 2; hf++) {
      bf16x8 afr[4], bg[4];
#pragma unroll
      for (int mb = 0; mb < 4; mb++)
        afr[mb] = *(const bf16x8*)&As[hf][(wm + mb * 16 + col) * 32 + quad * 8];
#pragma unroll
      for (int nb = 0; nb < 4; nb++)
        bg[nb] = *(const bf16x8*)&Bs[hf][(wn + nb * 16 + col) * 32 + quad * 8];
#pragma unroll
      for (int mb = 0; mb < 4; mb++)
#pragma unroll
        for (int nb = 0; nb < 4; nb++)
          acc[mb][nb] = mfma16(afr[mb], bg[nb], acc[mb][nb]);
    }
    __syncthreads();
  }

#pragma unroll
  for (int mb = 0; mb < 4; mb++) {
    const int mgq = m0 + wm + mb * 16 + quad * 4;  // 4 consecutive rows
    if (MODE == 0) {
      // rows are channels; third/h/d block-uniform-ish, d0 4-aligned
      const int third = mgq >> 10;
      const int nn0 = mgq & 1023;
      const int h = nn0 >> 6, d0 = nn0 & 63;
      float bs[4];
#pragma unroll
      for (int r = 0; r < 4; r++) bs[r] = bias[mgq + r];
#pragma unroll
      for (int nb = 0; nb < 4; nb++) {
        const int t = n0 + wn + nb * 16 + col;  // token
        const int bb = t >> 11, tt = t & 2047;
        const size_t bh = (size_t)bb * H_ + h;
        float v[4];
#pragma unroll
        for (int r = 0; r < 4; r++) v[r] = acc[mb][nb][r] + bs[r];
        if (third == 0) {
          bf16x4 y;
#pragma unroll
          for (int r = 0; r < 4; r++) y[r] = (bf16)v[r];
          *(bf16x4*)&((bf16*)o0)[(bh * T_ + tt) * D_ + d0] = y;
        } else if (third == 1) {
          const int lane2 = (tt & 15) | (((d0 >> 3) & 3) << 4);
          const size_t idx =
              ((((bh * 64 + (tt >> 5)) * 2 + ((tt >> 4) & 1)) * 2 + (d0 >> 5)) * 64 +
               lane2) * 8 + (d0 & 7);
          bf16x4 y;
#pragma unroll
          for (int r = 0; r < 4; r++) y[r] = (bf16)v[r];
          *(bf16x4*)&o1[idx] = y;
        } else {
#pragma unroll
          for (int r = 0; r < 4; r++) {
            const int d = d0 + r;
            const int lane2 = (d & 15) | (((tt >> 2) & 3) << 4);
            const size_t idx =
                (((bh * 64 + (tt >> 5)) * 4 + (d >> 4)) * 64 + lane2) * 8 +
                ((tt >> 4) & 1) * 4 + (tt & 3);
            o2[idx] = (f16)v[r];
          }
        }
      }
    } else {
#pragma unroll
      for (int nb = 0; nb < 4; nb++) {
        const int ng = n0 + wn + nb * 16 + col;
        const float bsc = bias[ng];
#pragma unroll
        for (int r = 0; r < 4; r++)
          ((float*)o0)[(size_t)(mgq + r) * N + ng] = acc[mb][nb][r] + bsc;
      }
    }
  }
}

// ---------------- flash attention: block = (bh, qtile); 4-way key split ----
// Q: [B,H,T,D] bf16; Kp/Vp: fragment-major (see gemm128); Y: [B,T,C] bf16
__global__ __launch_bounds__(256, 4) void attn(const bf16* __restrict__ Q,
                                               const bf16* __restrict__ Kp,
                                               const f16* __restrict__ Vp,
                                               bf16* __restrict__ Y) {
  const int tid = threadIdx.x, lane = tid & 63, wv = tid >> 6;
  const int col = lane & 15, quad = lane >> 4;
  const int id = blockIdx.x;
  const int j = id >> 3;
  const int bh = ((j & 7) << 3) | (id & 7);
  const int qtile = 63 - (j >> 3);  // longest blocks dispatch first
  const int b = bh >> 4, h = bh & 15;
  const int qbase = qtile * 32;

  __shared__ __align__(16) floatx4 mbuf[3][8][64];  // 24 KB partial-O
  __shared__ float lbuf[3][2][64];                  // 1.5 KB partial-lsum

  bf16x8 qf[2][2];
#pragma unroll
  for (int mq = 0; mq < 2; mq++) {
    const bf16* qp = Q + ((size_t)bh * T_ + qbase + mq * 16 + col) * D_ + quad * 8;
    qf[mq][0] = *(const bf16x8*)qp;
    qf[mq][1] = *(const bf16x8*)(qp + 32);
  }

  floatx4 o[2][4];  // O^T: dim = sub*16 + quad*4 + r, qrow = col
  float lsum[2] = {0.f, 0.f};
#pragma unroll
  for (int mq = 0; mq < 2; mq++)
#pragma unroll
    for (int s = 0; s < 4; s++) o[mq][s] = (floatx4){0.f, 0.f, 0.f, 0.f};

  const float C1 = 0.18033688f;  // 0.125*log2(e)
  const float C2 = 11.541560f;   // 8*log2(e): p = exp2(s*C1 - C2), exact softmax

  const int nmine = (qtile >= wv) ? ((qtile - wv) >> 2) + 1 : 0;

  for (int i = 0; i < nmine; i++) {
    const int kt = wv + 4 * i;
    const bool masked = (kt == qtile);
    const bf16* kbase = Kp + ((size_t)bh * 64 + kt) * 2048 + lane * 8;
    const f16* vbase = Vp + ((size_t)bh * 64 + kt) * 2048 + lane * 8;
    bf16x8 ka[2][2];
    ka[0][0] = *(const bf16x8*)(kbase);
    ka[0][1] = *(const bf16x8*)(kbase + 512);
    ka[1][0] = *(const bf16x8*)(kbase + 1024);
    ka[1][1] = *(const bf16x8*)(kbase + 1536);
    f16x8 vv[4];
#pragma unroll
    for (int sub = 0; sub < 4; sub++) vv[sub] = *(const f16x8*)(vbase + sub * 512);

#pragma unroll
    for (int st = 0; st < 2; st++) {
#pragma unroll
      for (int mq = 0; mq < 2; mq++) {
        if (masked && mq == 0 && st == 1) continue;  // fully masked sub-tile
        floatx4 s = (floatx4){0.f, 0.f, 0.f, 0.f};
        s = mfma16(ka[st][0], qf[mq][0], s);
        s = mfma16(ka[st][1], qf[mq][1], s);
        f16x4 pf;
        float ps = 0.f;
        const bool diag = masked && (mq == st);
#pragma unroll
        for (int r = 0; r < 4; r++) {
          float p = exp2f(fmaf(s[r], C1, -C2));
          if (diag && (quad * 4 + r > col)) p = 0.f;
          ps += p;
          pf[r] = (f16)p;
        }
        lsum[mq] += ps;
#pragma unroll
        for (int sub = 0; sub < 4; sub++) {
          f16x4 va;
#pragma unroll
          for (int jj = 0; jj < 4; jj++) va[jj] = vv[sub][st * 4 + jj];
          o[mq][sub] = mfma_pv(va, pf, o[mq][sub]);
        }
      }
    }
  }

  if (wv != 0) {
#pragma unroll
    for (int mq = 0; mq < 2; mq++) {
#pragma unroll
      for (int sub = 0; sub < 4; sub++) mbuf[wv - 1][mq * 4 + sub][lane] = o[mq][sub];
      lbuf[wv - 1][mq][lane] = lsum[mq];
    }
  }
  __syncthreads();
  if (wv == 0) {
#pragma unroll
    for (int w = 0; w < 3; w++)
#pragma unroll
      for (int mq = 0; mq < 2; mq++) {
#pragma unroll
        for (int sub = 0; sub < 4; sub++) o[mq][sub] += mbuf[w][mq * 4 + sub][lane];
        lsum[mq] += lbuf[w][mq][lane];
      }
#pragma unroll
    for (int mq = 0; mq < 2; mq++) {
      lsum[mq] += __shfl_xor(lsum[mq], 16);
      lsum[mq] += __shfl_xor(lsum[mq], 32);
      const float rinv = 1.f / lsum[mq];
      const int qrow = qbase + mq * 16 + col;
#pragma unroll
      for (int sub = 0; sub < 4; sub++) {
        bf16x4 yv;
#pragma unroll
        for (int r = 0; r < 4; r++) yv[r] = (bf16)(o[mq][sub][r] * rinv);
        *(bf16x4*)&Y[((size_t)b * T_ + qrow) * C_ + h * 64 + sub * 16 + quad * 4] = yv;
      }
    }
  }
}

extern "C" void kernel_launch(void* const* d_in, const int* in_sizes, int n_in,
                              void* d_out, int out_size, void* d_ws, size_t ws_size,
                              hipStream_t stream) {
  (void)in_sizes; (void)n_in; (void)out_size; (void)ws_size;
  const float* x      = (const float*)d_in[0];  // [B*T, C]
  const float* w_qkv  = (const float*)d_in[1];  // [C, 3C]
  const float* b_qkv  = (const float*)d_in[2];  // [3C]
  const float* w_proj = (const float*)d_in[3];  // [C, C]
  const float* b_proj = (const float*)d_in[4];  // [C]

  char* ws = (char*)d_ws;
  bf16* wqkv_t  = (bf16*)(ws);                  // [3C, C]   6291456 B
  bf16* wproj_t = (bf16*)(ws + 6291456);        // [C, C]    2097152 B
  bf16* qb      = (bf16*)(ws + 8388608);        // [B,H,T,D] 16777216 B
  bf16* kbuf    = (bf16*)(ws + 25165824);       // K frag-major 16777216 B
  f16*  vtbuf   = (f16*)(ws + 41943040);        // V frag-major 16777216 B
  bf16* yb      = (bf16*)(ws + 58720256);       // [B*T, C]  16777216 B
  bf16* xb      = (bf16*)(ws + 58720256);       // aliases yb (dead before attn)

  cvt_bf16<<<8192, 256, 0, stream>>>(x, xb);
  transpose_f32<<<dim3(96, 32), 256, 0, stream>>>(w_qkv, wqkv_t, 1024, 3072);
  transpose_f32<<<dim3(32, 32), 256, 0, stream>>>(w_proj, wproj_t, 1024, 1024);
  // SWAPPED: A = wqkv_t (channels), Bt = xb (tokens)
  gemm128<0><<<dim3(64, 24), 256, 0, stream>>>(wqkv_t, xb, b_qkv, qb, kbuf, vtbuf,
                                               3072, 8192, 1024);
  attn<<<dim3(4096), 256, 0, stream>>>(qb, kbuf, vtbuf, yb);
  gemm128<1><<<dim3(8, 64), 256, 0, stream>>>(yb, wproj_t, b_proj, d_out, nullptr,
                                              nullptr, 8192, 1024, 1024);
}